// Round 1
// baseline (252.148 us; speedup 1.0000x reference)
//
#include <hip/hip_runtime.h>
#include <hip/hip_bf16.h>
#include <cstdint>
#include <math.h>

#define D_DIM 1024
#define TAU_INV 10.0f

typedef __bf16 bf16x8 __attribute__((ext_vector_type(8)));
typedef float f32x4 __attribute__((ext_vector_type(4)));

__device__ __forceinline__ float wave_reduce_add(float v) {
#pragma unroll
    for (int off = 32; off > 0; off >>= 1) v += __shfl_xor(v, off, 64);
    return v;
}

// ---------------- Kernel A: normalize rows -> bf16 K, invnorm, zero rowsum --
__global__ __launch_bounds__(256)
void normalize_kernel(const float* __restrict__ zi, const float* __restrict__ zj,
                      __hip_bfloat16* __restrict__ K, float* __restrict__ invnorm,
                      float* __restrict__ rowsum, int n_half) {
    const int r = blockIdx.x;                 // 0 .. 2*n_half-1
    const int t = threadIdx.x;                // 256 threads, 4 floats each
    const float* src = (r < n_half) ? (zi + (size_t)r * D_DIM)
                                    : (zj + (size_t)(r - n_half) * D_DIM);
    float4 v = reinterpret_cast<const float4*>(src)[t];
    float ss = v.x * v.x + v.y * v.y + v.z * v.z + v.w * v.w;
    ss = wave_reduce_add(ss);
    __shared__ float ws4[4];
    if ((t & 63) == 0) ws4[t >> 6] = ss;
    __syncthreads();
    float tot = ws4[0] + ws4[1] + ws4[2] + ws4[3];
    float inv = 1.0f / sqrtf(tot);
    union { __hip_bfloat16 h[4]; uint2 u; } p;
    p.h[0] = __float2bfloat16(v.x * inv);
    p.h[1] = __float2bfloat16(v.y * inv);
    p.h[2] = __float2bfloat16(v.z * inv);
    p.h[3] = __float2bfloat16(v.w * inv);
    reinterpret_cast<uint2*>(K + (size_t)r * D_DIM)[t] = p.u;
    if (t == 0) { invnorm[r] = inv; rowsum[r] = 0.0f; }
}

// ---------------- Kernel B: positives[i] = dot(z_i[i], z_j[i]) * inv_i*inv_j --
__global__ __launch_bounds__(256)
void positives_kernel(const float* __restrict__ zi, const float* __restrict__ zj,
                      const float* __restrict__ invnorm, float* __restrict__ pos,
                      int n_half) {
    const int i = blockIdx.x;
    const int t = threadIdx.x;
    float4 a = reinterpret_cast<const float4*>(zi + (size_t)i * D_DIM)[t];
    float4 b = reinterpret_cast<const float4*>(zj + (size_t)i * D_DIM)[t];
    float d = a.x * b.x + a.y * b.y + a.z * b.z + a.w * b.w;
    d = wave_reduce_add(d);
    __shared__ float ws4[4];
    if ((t & 63) == 0) ws4[t >> 6] = d;
    __syncthreads();
    if (t == 0) pos[i] = (ws4[0] + ws4[1] + ws4[2] + ws4[3]) * invnorm[i] * invnorm[i + n_half];
}

// ---------------- Kernel C: S = K K^T tilewise; rowsum += sum_c!=r exp(10*S) --
// 128x128 tile, 4 waves (2x2), each wave 64x64 via 4x4 mfma_f32_16x16x32_bf16.
// LDS tiles [128 rows][64 bf16 = 128B] with XOR-16B-slot swizzle (T2):
//   physical slot p = logical slot s ^ (row&7).
// global_load_lds writes LDS linearly, so the global SOURCE address is
// inverse-swizzled (same involution), per rule #21.
__global__ __launch_bounds__(256)
void simclr_gemm_kernel(const __hip_bfloat16* __restrict__ K,
                        float* __restrict__ rowsum, int n_total) {
    __shared__ char lds[32768];
    char* ldsA = lds;
    char* ldsB = lds + 16384;

    const int tid  = threadIdx.x;
    const int lane = tid & 63;
    const int wave = tid >> 6;
    const int wr = wave >> 1, wc = wave & 1;
    const int rowbase = blockIdx.y * 128;
    const int colbase = blockIdx.x * 128;

    f32x4 acc[4][4] = {};

    const char* gK = reinterpret_cast<const char*>(K);
    const int rr  = tid >> 3;                  // staging row within 32-row group
    const int ssl = (tid & 7) ^ (rr & 7);      // inverse-swizzled source slot

    const int NKT = D_DIM / 64;                // 16 K-tiles of BK=64
    for (int kt = 0; kt < NKT; ++kt) {
        __syncthreads();                        // all waves done reading prev tile
        const size_t kbyte = (size_t)kt * 128;  // 64 bf16 = 128 B per row chunk
#pragma unroll
        for (int c = 0; c < 4; ++c) {
            const int r = c * 32 + rr;
            const char* srcA = gK + (size_t)(rowbase + r) * 2048 + kbyte + ssl * 16;
            const char* srcB = gK + (size_t)(colbase + r) * 2048 + kbyte + ssl * 16;
            __builtin_amdgcn_global_load_lds(
                (const __attribute__((address_space(1))) void*)srcA,
                (__attribute__((address_space(3))) void*)(ldsA + c * 4096 + tid * 16),
                16, 0, 0);
            __builtin_amdgcn_global_load_lds(
                (const __attribute__((address_space(1))) void*)srcB,
                (__attribute__((address_space(3))) void*)(ldsB + c * 4096 + tid * 16),
                16, 0, 0);
        }
        __syncthreads();                        // vmcnt(0) drained before barrier
#pragma unroll
        for (int kk = 0; kk < 2; ++kk) {
            bf16x8 af[4], bf[4];
            const int slot = kk * 4 + (lane >> 4);  // 16B slot within 128B row
#pragma unroll
            for (int mi = 0; mi < 4; ++mi) {
                const int row = wr * 64 + mi * 16 + (lane & 15);
                af[mi] = *reinterpret_cast<const bf16x8*>(
                    ldsA + row * 128 + ((slot ^ (row & 7)) << 4));
            }
#pragma unroll
            for (int ni = 0; ni < 4; ++ni) {
                const int row = wc * 64 + ni * 16 + (lane & 15);
                bf[ni] = *reinterpret_cast<const bf16x8*>(
                    ldsB + row * 128 + ((slot ^ (row & 7)) << 4));
            }
#pragma unroll
            for (int mi = 0; mi < 4; ++mi)
#pragma unroll
                for (int ni = 0; ni < 4; ++ni)
                    acc[mi][ni] = __builtin_amdgcn_mfma_f32_16x16x32_bf16(
                        af[mi], bf[ni], acc[mi][ni], 0, 0, 0);
        }
    }

    // Epilogue: exp(10*s) excluding diagonal; per-row reduce over 16 lanes; atomicAdd.
#pragma unroll
    for (int mi = 0; mi < 4; ++mi) {
#pragma unroll
        for (int reg = 0; reg < 4; ++reg) {
            const int grow = rowbase + wr * 64 + mi * 16 + ((lane >> 4) << 2) + reg;
            float partial = 0.0f;
#pragma unroll
            for (int ni = 0; ni < 4; ++ni) {
                const int gcol = colbase + wc * 64 + ni * 16 + (lane & 15);
                const float s = acc[mi][ni][reg];
                partial += (grow == gcol) ? 0.0f : __expf(s * TAU_INV);
            }
#pragma unroll
            for (int off = 1; off < 16; off <<= 1)
                partial += __shfl_xor(partial, off, 64);
            if ((lane & 15) == 0) atomicAdd(&rowsum[grow], partial);
        }
    }
    (void)n_total;
}

// ---------------- Kernel D: loss = mean(log(denom) - pos/tau) ---------------
__global__ __launch_bounds__(256)
void loss_kernel(const float* __restrict__ rowsum, const float* __restrict__ pos,
                 float* __restrict__ out, int n_total, int n_half) {
    const int t = threadIdx.x;
    float acc = 0.0f;
    for (int r = t; r < n_total; r += 256) {
        const int pi = (r < n_half) ? r : (r - n_half);
        acc += logf(rowsum[r]) - TAU_INV * pos[pi];
    }
    acc = wave_reduce_add(acc);
    __shared__ float ws4[4];
    if ((t & 63) == 0) ws4[t >> 6] = acc;
    __syncthreads();
    if (t == 0) out[0] = (ws4[0] + ws4[1] + ws4[2] + ws4[3]) / (float)n_total;
}

extern "C" void kernel_launch(void* const* d_in, const int* in_sizes, int n_in,
                              void* d_out, int out_size, void* d_ws, size_t ws_size,
                              hipStream_t stream) {
    const float* zi = (const float*)d_in[0];
    const float* zj = (const float*)d_in[1];
    float* out = (float*)d_out;

    const int n_half  = in_sizes[0] / D_DIM;   // 4096
    const int n_total = 2 * n_half;            // 8192

    // workspace layout
    char* ws = (char*)d_ws;
    __hip_bfloat16* K = (__hip_bfloat16*)ws;                       // n_total * D * 2 B
    size_t off = (size_t)n_total * D_DIM * sizeof(__hip_bfloat16);
    float* rowsum  = (float*)(ws + off); off += (size_t)n_total * 4;
    float* invnorm = (float*)(ws + off); off += (size_t)n_total * 4;
    float* pos     = (float*)(ws + off); off += (size_t)n_half * 4;

    normalize_kernel<<<n_total, 256, 0, stream>>>(zi, zj, K, invnorm, rowsum, n_half);
    positives_kernel<<<n_half, 256, 0, stream>>>(zi, zj, invnorm, pos, n_half);
    dim3 grid(n_total / 128, n_total / 128);
    simclr_gemm_kernel<<<grid, 256, 0, stream>>>(K, rowsum, n_total);
    loss_kernel<<<1, 256, 0, stream>>>(rowsum, pos, out, n_total, n_half);
}

// Round 2
// 173.300 us; speedup vs baseline: 1.4550x; 1.4550x over previous
//
#include <hip/hip_runtime.h>
#include <hip/hip_bf16.h>
#include <cstdint>
#include <math.h>

#define D_DIM 1024
#define TAU_INV 10.0f

typedef __bf16 bf16x8 __attribute__((ext_vector_type(8)));
typedef float f32x4 __attribute__((ext_vector_type(4)));

__device__ __forceinline__ float wave_reduce_add(float v) {
#pragma unroll
    for (int off = 32; off > 0; off >>= 1) v += __shfl_xor(v, off, 64);
    return v;
}

// ---------------- Kernel A: normalize rows -> bf16 K, invnorm, zero rowsum --
__global__ __launch_bounds__(256)
void normalize_kernel(const float* __restrict__ zi, const float* __restrict__ zj,
                      __hip_bfloat16* __restrict__ K, float* __restrict__ invnorm,
                      float* __restrict__ rowsum, int n_half) {
    const int r = blockIdx.x;                 // 0 .. 2*n_half-1
    const int t = threadIdx.x;                // 256 threads, 4 floats each
    const float* src = (r < n_half) ? (zi + (size_t)r * D_DIM)
                                    : (zj + (size_t)(r - n_half) * D_DIM);
    float4 v = reinterpret_cast<const float4*>(src)[t];
    float ss = v.x * v.x + v.y * v.y + v.z * v.z + v.w * v.w;
    ss = wave_reduce_add(ss);
    __shared__ float ws4[4];
    if ((t & 63) == 0) ws4[t >> 6] = ss;
    __syncthreads();
    float tot = ws4[0] + ws4[1] + ws4[2] + ws4[3];
    float inv = 1.0f / sqrtf(tot);
    union { __hip_bfloat16 h[4]; uint2 u; } p;
    p.h[0] = __float2bfloat16(v.x * inv);
    p.h[1] = __float2bfloat16(v.y * inv);
    p.h[2] = __float2bfloat16(v.z * inv);
    p.h[3] = __float2bfloat16(v.w * inv);
    reinterpret_cast<uint2*>(K + (size_t)r * D_DIM)[t] = p.u;
    if (t == 0) { invnorm[r] = inv; rowsum[r] = 0.0f; }
}

// ---------------- Kernel B: positives[i] = dot(z_i[i], z_j[i]) * inv_i*inv_j --
__global__ __launch_bounds__(256)
void positives_kernel(const float* __restrict__ zi, const float* __restrict__ zj,
                      const float* __restrict__ invnorm, float* __restrict__ pos,
                      int n_half) {
    const int i = blockIdx.x;
    const int t = threadIdx.x;
    float4 a = reinterpret_cast<const float4*>(zi + (size_t)i * D_DIM)[t];
    float4 b = reinterpret_cast<const float4*>(zj + (size_t)i * D_DIM)[t];
    float d = a.x * b.x + a.y * b.y + a.z * b.z + a.w * b.w;
    d = wave_reduce_add(d);
    __shared__ float ws4[4];
    if ((t & 63) == 0) ws4[t >> 6] = d;
    __syncthreads();
    if (t == 0) pos[i] = (ws4[0] + ws4[1] + ws4[2] + ws4[3]) * invnorm[i] * invnorm[i + n_half];
}

// ---------------- Kernel C: upper-triangular tiles of S = K K^T -------------
// Symmetry: S[r,c] = S[c,r], and we only need rowsum[r] = sum_c exp(10*S[r,c]).
// So compute only tiles with bx >= by. Off-diagonal tiles contribute their
// row-reduction to rowsum[rows] AND their column-reduction to rowsum[cols].
// Diagonal tiles (bx==by) contribute row-reduction only, excluding the diag.
// 128x128 tile, 4 waves (2x2), each wave 64x64 via 4x4 mfma_f32_16x16x32_bf16.
// LDS tiles [128 rows][64 bf16 = 128B] with XOR-16B-slot swizzle (T2), rule
// #21: inverse-swizzled global SOURCE + swizzled ds_read (verified round 1:
// SQ_LDS_BANK_CONFLICT == 0).
__global__ __launch_bounds__(256)
void simclr_gemm_kernel(const __hip_bfloat16* __restrict__ K,
                        float* __restrict__ rowsum, int n_total) {
    if (blockIdx.x < blockIdx.y) return;       // lower triangle: skip
    const bool diag = (blockIdx.x == blockIdx.y);

    __shared__ char lds[32768];
    char* ldsA = lds;
    char* ldsB = lds + 16384;

    const int tid  = threadIdx.x;
    const int lane = tid & 63;
    const int wave = tid >> 6;
    const int wr = wave >> 1, wc = wave & 1;
    const int rowbase = blockIdx.y * 128;
    const int colbase = blockIdx.x * 128;

    f32x4 acc[4][4] = {};

    const char* gK = reinterpret_cast<const char*>(K);
    const int rr  = tid >> 3;                  // staging row within 32-row group
    const int ssl = (tid & 7) ^ (rr & 7);      // inverse-swizzled source slot

    const int NKT = D_DIM / 64;                // 16 K-tiles of BK=64
    for (int kt = 0; kt < NKT; ++kt) {
        __syncthreads();                        // all waves done reading prev tile
        const size_t kbyte = (size_t)kt * 128;  // 64 bf16 = 128 B per row chunk
#pragma unroll
        for (int c = 0; c < 4; ++c) {
            const int r = c * 32 + rr;
            const char* srcA = gK + (size_t)(rowbase + r) * 2048 + kbyte + ssl * 16;
            const char* srcB = gK + (size_t)(colbase + r) * 2048 + kbyte + ssl * 16;
            __builtin_amdgcn_global_load_lds(
                (const __attribute__((address_space(1))) void*)srcA,
                (__attribute__((address_space(3))) void*)(ldsA + c * 4096 + tid * 16),
                16, 0, 0);
            __builtin_amdgcn_global_load_lds(
                (const __attribute__((address_space(1))) void*)srcB,
                (__attribute__((address_space(3))) void*)(ldsB + c * 4096 + tid * 16),
                16, 0, 0);
        }
        __syncthreads();                        // vmcnt(0) drained before barrier
#pragma unroll
        for (int kk = 0; kk < 2; ++kk) {
            bf16x8 af[4], bf[4];
            const int slot = kk * 4 + (lane >> 4);  // 16B slot within 128B row
#pragma unroll
            for (int mi = 0; mi < 4; ++mi) {
                const int row = wr * 64 + mi * 16 + (lane & 15);
                af[mi] = *reinterpret_cast<const bf16x8*>(
                    ldsA + row * 128 + ((slot ^ (row & 7)) << 4));
            }
#pragma unroll
            for (int ni = 0; ni < 4; ++ni) {
                const int row = wc * 64 + ni * 16 + (lane & 15);
                bf[ni] = *reinterpret_cast<const bf16x8*>(
                    ldsB + row * 128 + ((slot ^ (row & 7)) << 4));
            }
#pragma unroll
            for (int mi = 0; mi < 4; ++mi)
#pragma unroll
                for (int ni = 0; ni < 4; ++ni)
                    acc[mi][ni] = __builtin_amdgcn_mfma_f32_16x16x32_bf16(
                        af[mi], bf[ni], acc[mi][ni], 0, 0, 0);
        }
    }

    // Epilogue. C-fragment layout: col = lane&15, row = (lane>>4)*4 + reg.
    // Row partials -> rowsum[rows]; for off-diag tiles also column partials
    // -> rowsum[cols] (S is symmetric, so col c's row-sum gets this tile's
    // column reduction).
    float colpart[4] = {0.0f, 0.0f, 0.0f, 0.0f};
#pragma unroll
    for (int mi = 0; mi < 4; ++mi) {
#pragma unroll
        for (int reg = 0; reg < 4; ++reg) {
            const int grow = rowbase + wr * 64 + mi * 16 + ((lane >> 4) << 2) + reg;
            float rowpart = 0.0f;
#pragma unroll
            for (int ni = 0; ni < 4; ++ni) {
                const int gcol = colbase + wc * 64 + ni * 16 + (lane & 15);
                float e = __expf(acc[mi][ni][reg] * TAU_INV);
                if (diag && grow == gcol) e = 0.0f;
                rowpart += e;
                colpart[ni] += e;
            }
#pragma unroll
            for (int off = 1; off < 16; off <<= 1)
                rowpart += __shfl_xor(rowpart, off, 64);
            if ((lane & 15) == 0) atomicAdd(&rowsum[grow], rowpart);
        }
    }
    if (!diag) {
#pragma unroll
        for (int ni = 0; ni < 4; ++ni) {
            float cp = colpart[ni];
            cp += __shfl_xor(cp, 16, 64);
            cp += __shfl_xor(cp, 32, 64);
            if (lane < 16)
                atomicAdd(&rowsum[colbase + wc * 64 + ni * 16 + lane], cp);
        }
    }
    (void)n_total;
}

// ---------------- Kernel D: loss = mean(log(denom) - pos/tau) ---------------
__global__ __launch_bounds__(256)
void loss_kernel(const float* __restrict__ rowsum, const float* __restrict__ pos,
                 float* __restrict__ out, int n_total, int n_half) {
    const int t = threadIdx.x;
    float acc = 0.0f;
    for (int r = t; r < n_total; r += 256) {
        const int pi = (r < n_half) ? r : (r - n_half);
        acc += logf(rowsum[r]) - TAU_INV * pos[pi];
    }
    acc = wave_reduce_add(acc);
    __shared__ float ws4[4];
    if ((t & 63) == 0) ws4[t >> 6] = acc;
    __syncthreads();
    if (t == 0) out[0] = (ws4[0] + ws4[1] + ws4[2] + ws4[3]) / (float)n_total;
}

extern "C" void kernel_launch(void* const* d_in, const int* in_sizes, int n_in,
                              void* d_out, int out_size, void* d_ws, size_t ws_size,
                              hipStream_t stream) {
    const float* zi = (const float*)d_in[0];
    const float* zj = (const float*)d_in[1];
    float* out = (float*)d_out;

    const int n_half  = in_sizes[0] / D_DIM;   // 4096
    const int n_total = 2 * n_half;            // 8192

    // workspace layout
    char* ws = (char*)d_ws;
    __hip_bfloat16* K = (__hip_bfloat16*)ws;                       // n_total * D * 2 B
    size_t off = (size_t)n_total * D_DIM * sizeof(__hip_bfloat16);
    float* rowsum  = (float*)(ws + off); off += (size_t)n_total * 4;
    float* invnorm = (float*)(ws + off); off += (size_t)n_total * 4;
    float* pos     = (float*)(ws + off); off += (size_t)n_half * 4;

    normalize_kernel<<<n_total, 256, 0, stream>>>(zi, zj, K, invnorm, rowsum, n_half);
    positives_kernel<<<n_half, 256, 0, stream>>>(zi, zj, invnorm, pos, n_half);
    dim3 grid(n_total / 128, n_total / 128);
    simclr_gemm_kernel<<<grid, 256, 0, stream>>>(K, rowsum, n_total);
    loss_kernel<<<1, 256, 0, stream>>>(rowsum, pos, out, n_total, n_half);
}

// Round 3
// 151.143 us; speedup vs baseline: 1.6683x; 1.1466x over previous
//
#include <hip/hip_runtime.h>
#include <hip/hip_bf16.h>
#include <cstdint>
#include <math.h>

#define D_DIM 1024
#define TAU_INV 10.0f
#define BK 32
#define NT (D_DIM / BK)        // 32 K-steps
#define BM 256

typedef __bf16 bf16x8 __attribute__((ext_vector_type(8)));
typedef float f32x4 __attribute__((ext_vector_type(4)));

#define VMCNT(n) asm volatile("s_waitcnt vmcnt(" #n ")" ::: "memory")
#define CFENCE() asm volatile("" ::: "memory")

__device__ __forceinline__ float wave_reduce_add(float v) {
#pragma unroll
    for (int off = 32; off > 0; off >>= 1) v += __shfl_xor(v, off, 64);
    return v;
}

// ---- Kernel A (fused): normalize both rows -> bf16 K, positives, zero rowsum
__global__ __launch_bounds__(256)
void norm_pos_kernel(const float* __restrict__ zi, const float* __restrict__ zj,
                     __hip_bfloat16* __restrict__ K, float* __restrict__ rowsum,
                     float* __restrict__ pos, int n_half) {
    const int i = blockIdx.x;
    const int t = threadIdx.x;                 // 256 threads x 4 floats = 1024
    float4 a = reinterpret_cast<const float4*>(zi + (size_t)i * D_DIM)[t];
    float4 b = reinterpret_cast<const float4*>(zj + (size_t)i * D_DIM)[t];
    float ssa = a.x*a.x + a.y*a.y + a.z*a.z + a.w*a.w;
    float ssb = b.x*b.x + b.y*b.y + b.z*b.z + b.w*b.w;
    float dab = a.x*b.x + a.y*b.y + a.z*b.z + a.w*b.w;
    ssa = wave_reduce_add(ssa);
    ssb = wave_reduce_add(ssb);
    dab = wave_reduce_add(dab);
    __shared__ float wsa[4], wsb[4], wsd[4];
    if ((t & 63) == 0) { wsa[t>>6] = ssa; wsb[t>>6] = ssb; wsd[t>>6] = dab; }
    __syncthreads();
    const float inva = 1.0f / sqrtf(wsa[0] + wsa[1] + wsa[2] + wsa[3]);
    const float invb = 1.0f / sqrtf(wsb[0] + wsb[1] + wsb[2] + wsb[3]);
    union { __hip_bfloat16 h[4]; uint2 u; } pa, pb;
    pa.h[0] = __float2bfloat16(a.x * inva); pa.h[1] = __float2bfloat16(a.y * inva);
    pa.h[2] = __float2bfloat16(a.z * inva); pa.h[3] = __float2bfloat16(a.w * inva);
    pb.h[0] = __float2bfloat16(b.x * invb); pb.h[1] = __float2bfloat16(b.y * invb);
    pb.h[2] = __float2bfloat16(b.z * invb); pb.h[3] = __float2bfloat16(b.w * invb);
    reinterpret_cast<uint2*>(K + (size_t)i * D_DIM)[t] = pa.u;
    reinterpret_cast<uint2*>(K + (size_t)(i + n_half) * D_DIM)[t] = pb.u;
    if (t == 0) {
        pos[i] = (wsd[0] + wsd[1] + wsd[2] + wsd[3]) * inva * invb;
        rowsum[i] = 0.0f;
        rowsum[i + n_half] = 0.0f;
    }
}

// ---- Kernel B: upper-triangular 256x256 tiles of S = K K^T ------------------
// 8 waves (2x4), per-wave 128x64 output (acc[8][4] of 16x16 frags), BK=32.
// 4-slot LDS ring, depth-3 prefetch with counted vmcnt(8): tile t resident is
// guaranteed by (vmcnt(8) -> all but tiles t+1,t+2 complete) + s_barrier.
// Slot (t+3)&3 == slot (t-1)&3 was last read at step t-1, whose reads complete
// before this step's barrier -> no write-while-read.
// BK=32 rows are 64B: fragment reads hit bank 16*(row&1)+4*kgrp -> all 32
// banks covered minimally, no swizzle required.
__global__ __launch_bounds__(512, 2)
void simclr_gemm_kernel(const __hip_bfloat16* __restrict__ Kmat,
                        float* __restrict__ rowsum, int n_total) {
    __shared__ char lds[131072];
    char* ldsA = lds;
    char* ldsB = lds + 65536;

    const int tid  = threadIdx.x;
    const int lane = tid & 63;
    const int wave = tid >> 6;          // 0..7
    const int wr = wave >> 2;           // 0..1  (M panel)
    const int wc = wave & 3;            // 0..3  (N panel)
    const int kgrp = lane >> 4;         // 16B k-slot within 64B row

    // bijective XCD swizzle (m204 variant) over the compact triangular grid
    const int nwg = gridDim.x;
    const int q = nwg >> 3, r = nwg & 7;
    const int xcd = blockIdx.x & 7, loc = blockIdx.x >> 3;
    const int wg = (xcd < r ? xcd * (q + 1) : r * (q + 1) + (xcd - r) * q) + loc;

    // decode wg -> (by, bx), by <= bx < NB
    const int NB = n_total / BM;
    int by = (int)((2.0f * NB + 1.0f -
                    sqrtf((2.0f * NB + 1.0f) * (2.0f * NB + 1.0f) - 8.0f * (float)wg)) * 0.5f);
    if (by >= NB) by = NB - 1;
    if (by < 0) by = 0;
    int start = by * NB - (by * (by - 1)) / 2;
    while (start > wg) { --by; start = by * NB - (by * (by - 1)) / 2; }
    while (wg - start >= NB - by) { start += NB - by; ++by; }
    const int bx = by + (wg - start);
    const bool diag = (bx == by);
    const int rowbase = by * BM;
    const int colbase = bx * BM;

    const char* gK = reinterpret_cast<const char*>(Kmat);
    const int srow  = tid >> 2;          // staging row 0..127 per 8KB issue
    const int sslot = tid & 3;           // 16B slot within 64B row

    auto stage = [&](int t) {
        const int s = t & 3;
        const size_t kbyte = (size_t)t * (BK * 2);
#pragma unroll
        for (int a = 0; a < 2; ++a) {
            const int row = a * 128 + srow;
            const char* srcA = gK + (size_t)(rowbase + row) * (D_DIM * 2) + kbyte + sslot * 16;
            const char* srcB = gK + (size_t)(colbase + row) * (D_DIM * 2) + kbyte + sslot * 16;
            __builtin_amdgcn_global_load_lds(
                (const __attribute__((address_space(1))) void*)srcA,
                (__attribute__((address_space(3))) void*)(ldsA + s * 16384 + a * 8192 + tid * 16),
                16, 0, 0);
            __builtin_amdgcn_global_load_lds(
                (const __attribute__((address_space(1))) void*)srcB,
                (__attribute__((address_space(3))) void*)(ldsB + s * 16384 + a * 8192 + tid * 16),
                16, 0, 0);
        }
    };

    f32x4 acc[8][4] = {};

    auto step = [&](int t, bool prefetch) {
        __builtin_amdgcn_s_barrier();    // all waves: tile t resident, slot (t+3)&3 free
        CFENCE();
        if (prefetch) stage(t + 3);
        const char* Ab = ldsA + (t & 3) * 16384;
        const char* Bb = ldsB + (t & 3) * 16384;
        bf16x8 af[8], bfr[4];
#pragma unroll
        for (int mi = 0; mi < 8; ++mi)
            af[mi] = *reinterpret_cast<const bf16x8*>(
                Ab + (wr * 128 + mi * 16 + (lane & 15)) * 64 + (kgrp << 4));
#pragma unroll
        for (int ni = 0; ni < 4; ++ni)
            bfr[ni] = *reinterpret_cast<const bf16x8*>(
                Bb + (wc * 64 + ni * 16 + (lane & 15)) * 64 + (kgrp << 4));
        __builtin_amdgcn_s_setprio(1);
#pragma unroll
        for (int mi = 0; mi < 8; ++mi)
#pragma unroll
            for (int ni = 0; ni < 4; ++ni)
                acc[mi][ni] = __builtin_amdgcn_mfma_f32_16x16x32_bf16(
                    af[mi], bfr[ni], acc[mi][ni], 0, 0, 0);
        __builtin_amdgcn_s_setprio(0);
    };

    // prologue: 3 tiles in flight (12 loads/wave)
    stage(0); stage(1); stage(2);
    for (int t = 0; t < NT - 2; ++t) { VMCNT(8); step(t, t + 3 < NT); }
    VMCNT(4); step(NT - 2, false);
    VMCNT(0); step(NT - 1, false);

    // Epilogue. C-frag: col = lane&15, row = (lane>>4)*4 + reg.
    // Row-reduce -> rowsum[rows]; off-diag tiles also column-reduce -> rowsum[cols].
    float colpart[4] = {0.0f, 0.0f, 0.0f, 0.0f};
#pragma unroll
    for (int mi = 0; mi < 8; ++mi) {
#pragma unroll
        for (int reg = 0; reg < 4; ++reg) {
            const int grow = rowbase + wr * 128 + mi * 16 + ((lane >> 4) << 2) + reg;
            float rowpart = 0.0f;
#pragma unroll
            for (int ni = 0; ni < 4; ++ni) {
                const int gcol = colbase + wc * 64 + ni * 16 + (lane & 15);
                float e = __expf(acc[mi][ni][reg] * TAU_INV);
                if (diag && grow == gcol) e = 0.0f;
                rowpart += e;
                colpart[ni] += e;
            }
#pragma unroll
            for (int off = 1; off < 16; off <<= 1)
                rowpart += __shfl_xor(rowpart, off, 64);
            if ((lane & 15) == 0) atomicAdd(&rowsum[grow], rowpart);
        }
    }
    if (!diag) {
#pragma unroll
        for (int ni = 0; ni < 4; ++ni) {
            float cp = colpart[ni];
            cp += __shfl_xor(cp, 16, 64);
            cp += __shfl_xor(cp, 32, 64);
            if (lane < 16)
                atomicAdd(&rowsum[colbase + wc * 64 + ni * 16 + lane], cp);
        }
    }
}

// ---- Kernel C: loss = mean(log(denom) - pos/tau) ---------------------------
__global__ __launch_bounds__(256)
void loss_kernel(const float* __restrict__ rowsum, const float* __restrict__ pos,
                 float* __restrict__ out, int n_total, int n_half) {
    const int t = threadIdx.x;
    float acc = 0.0f;
    for (int r = t; r < n_total; r += 256) {
        const int pi = (r < n_half) ? r : (r - n_half);
        acc += logf(rowsum[r]) - TAU_INV * pos[pi];
    }
    acc = wave_reduce_add(acc);
    __shared__ float ws4[4];
    if ((t & 63) == 0) ws4[t >> 6] = acc;
    __syncthreads();
    if (t == 0) out[0] = (ws4[0] + ws4[1] + ws4[2] + ws4[3]) / (float)n_total;
}

extern "C" void kernel_launch(void* const* d_in, const int* in_sizes, int n_in,
                              void* d_out, int out_size, void* d_ws, size_t ws_size,
                              hipStream_t stream) {
    const float* zi = (const float*)d_in[0];
    const float* zj = (const float*)d_in[1];
    float* out = (float*)d_out;

    const int n_half  = in_sizes[0] / D_DIM;   // 4096
    const int n_total = 2 * n_half;            // 8192

    char* ws = (char*)d_ws;
    __hip_bfloat16* K = (__hip_bfloat16*)ws;
    size_t off = (size_t)n_total * D_DIM * sizeof(__hip_bfloat16);
    float* rowsum = (float*)(ws + off); off += (size_t)n_total * 4;
    float* pos    = (float*)(ws + off); off += (size_t)n_half * 4;

    norm_pos_kernel<<<n_half, 256, 0, stream>>>(zi, zj, K, rowsum, pos, n_half);

    const int NB = n_total / BM;               // 32
    const int nblk = NB * (NB + 1) / 2;        // 528
    simclr_gemm_kernel<<<nblk, 512, 0, stream>>>(K, rowsum, n_total);

    loss_kernel<<<1, 256, 0, stream>>>(rowsum, pos, out, n_total, n_half);
}

// Round 4
// 135.081 us; speedup vs baseline: 1.8666x; 1.1189x over previous
//
#include <hip/hip_runtime.h>
#include <hip/hip_bf16.h>
#include <cstdint>
#include <math.h>

#define D_DIM 1024
#define TAU_INV 10.0f
#define BK 32
#define NT (D_DIM / BK)        // 32 K-steps
#define BM 256                 // A-tile rows
#define BN 128                 // B-tile rows (cols of S)

typedef __bf16 bf16x8 __attribute__((ext_vector_type(8)));
typedef float f32x4 __attribute__((ext_vector_type(4)));

#define VMCNT(n) asm volatile("s_waitcnt vmcnt(" #n ")" ::: "memory")
#define CFENCE() asm volatile("" ::: "memory")

__device__ __forceinline__ float wave_reduce_add(float v) {
#pragma unroll
    for (int off = 32; off > 0; off >>= 1) v += __shfl_xor(v, off, 64);
    return v;
}

// ---- Kernel A (fused): normalize both rows -> bf16 K, positives, zero rowsum
__global__ __launch_bounds__(256)
void norm_pos_kernel(const float* __restrict__ zi, const float* __restrict__ zj,
                     __hip_bfloat16* __restrict__ K, float* __restrict__ rowsum,
                     float* __restrict__ pos, int n_half) {
    const int i = blockIdx.x;
    const int t = threadIdx.x;                 // 256 threads x 4 floats = 1024
    float4 a = reinterpret_cast<const float4*>(zi + (size_t)i * D_DIM)[t];
    float4 b = reinterpret_cast<const float4*>(zj + (size_t)i * D_DIM)[t];
    float ssa = a.x*a.x + a.y*a.y + a.z*a.z + a.w*a.w;
    float ssb = b.x*b.x + b.y*b.y + b.z*b.z + b.w*b.w;
    float dab = a.x*b.x + a.y*b.y + a.z*b.z + a.w*b.w;
    ssa = wave_reduce_add(ssa);
    ssb = wave_reduce_add(ssb);
    dab = wave_reduce_add(dab);
    __shared__ float wsa[4], wsb[4], wsd[4];
    if ((t & 63) == 0) { wsa[t>>6] = ssa; wsb[t>>6] = ssb; wsd[t>>6] = dab; }
    __syncthreads();
    const float inva = 1.0f / sqrtf(wsa[0] + wsa[1] + wsa[2] + wsa[3]);
    const float invb = 1.0f / sqrtf(wsb[0] + wsb[1] + wsb[2] + wsb[3]);
    union { __hip_bfloat16 h[4]; uint2 u; } pa, pb;
    pa.h[0] = __float2bfloat16(a.x * inva); pa.h[1] = __float2bfloat16(a.y * inva);
    pa.h[2] = __float2bfloat16(a.z * inva); pa.h[3] = __float2bfloat16(a.w * inva);
    pb.h[0] = __float2bfloat16(b.x * invb); pb.h[1] = __float2bfloat16(b.y * invb);
    pb.h[2] = __float2bfloat16(b.z * invb); pb.h[3] = __float2bfloat16(b.w * invb);
    reinterpret_cast<uint2*>(K + (size_t)i * D_DIM)[t] = pa.u;
    reinterpret_cast<uint2*>(K + (size_t)(i + n_half) * D_DIM)[t] = pb.u;
    if (t == 0) {
        pos[i] = (wsd[0] + wsd[1] + wsd[2] + wsd[3]) * inva * invb;
        rowsum[i] = 0.0f;
        rowsum[i + n_half] = 0.0f;
    }
}

// ---- Kernel B: triangular 256x128 tiles of S = K K^T -----------------------
// Tiles: by in [0,32) over 256-row blocks, bx in [0,64) over 128-col blocks,
// computed iff bx >= 2*by. "diag" tiles (bx>>1 == by) lie entirely within a
// 256-row symmetric block: contribute row-reduction only (pairs appear twice
// across the computed set), zeroing exact diagonal. Other tiles appear once:
// contribute row-reduction AND column-reduction (symmetry).
// 8 waves (2M x 4N), per-wave 128x32 output = acc[8][2] (64 VGPRs).
// Ring-3 LDS (72 KiB total -> 2 blocks/CU), depth-2 prefetch, counted vmcnt:
//   per wave 3 global_load_lds per tile; VMCNT(3) -> own stage(t) complete ->
//   s_barrier publishes residency; stage(t+2) AFTER barrier into slot
//   (t+2)%3 == (t-1)%3, whose readers finished before this barrier.
// LDS swizzle for 64B rows: 16B slot p holds logical slot p ^ ((row>>1)&3);
// staging source pre-applies the same involution (rule #21).
__global__ __launch_bounds__(512, 4)
void simclr_gemm_kernel(const __hip_bfloat16* __restrict__ Kmat,
                        float* __restrict__ rowsum, int n_total) {
    __shared__ char lds[73728];
    char* ldsA = lds;                       // 3 slots x 16 KiB
    char* ldsB = lds + 49152;               // 3 slots x 8 KiB

    const int tid  = threadIdx.x;
    const int lane = tid & 63;
    const int wave = tid >> 6;          // 0..7
    const int wr = wave >> 2;           // 0..1  (M panel: 128 rows)
    const int wc = wave & 3;            // 0..3  (N panel: 32 cols)
    const int kgrp = lane >> 4;         // 16B k-slot within 64B row

    // bijective XCD swizzle (nwg = 1056, divisible by 8)
    const int nwg = gridDim.x;
    const int q = nwg >> 3;
    const int wg = (blockIdx.x & 7) * q + (blockIdx.x >> 3);

    // decode wg -> (by, bx): by in [0,32), bx in [2*by, 64)
    int by = 0, start = 0;
    while (wg >= start + (64 - 2 * by)) { start += 64 - 2 * by; ++by; }
    const int bx = 2 * by + (wg - start);
    const bool diag = ((bx >> 1) == by);
    const int rowbase = by * BM;
    const int colbase = bx * BN;

    const char* gK = reinterpret_cast<const char*>(Kmat);
    const int srow  = tid >> 2;          // staging row 0..127 per 8KB issue
    const int sswz  = (tid & 3) ^ ((srow >> 1) & 3);  // inverse-swizzled slot

    auto stage = [&](int t) {
        const int s = t % 3;
        const size_t kbyte = (size_t)t * (BK * 2);
#pragma unroll
        for (int a = 0; a < 2; ++a) {
            const int row = a * 128 + srow;
            const char* srcA = gK + (size_t)(rowbase + row) * (D_DIM * 2) + kbyte + sswz * 16;
            __builtin_amdgcn_global_load_lds(
                (const __attribute__((address_space(1))) void*)srcA,
                (__attribute__((address_space(3))) void*)(ldsA + s * 16384 + a * 8192 + tid * 16),
                16, 0, 0);
        }
        const char* srcB = gK + (size_t)(colbase + srow) * (D_DIM * 2) + kbyte + sswz * 16;
        __builtin_amdgcn_global_load_lds(
            (const __attribute__((address_space(1))) void*)srcB,
            (__attribute__((address_space(3))) void*)(ldsB + s * 8192 + tid * 16),
            16, 0, 0);
    };

    f32x4 acc[8][2] = {};

    auto compute = [&](int t) {
        const char* Ab = ldsA + (t % 3) * 16384;
        const char* Bb = ldsB + (t % 3) * 8192;
        bf16x8 bfr[2];
#pragma unroll
        for (int ni = 0; ni < 2; ++ni) {
            const int rB = wc * 32 + ni * 16 + (lane & 15);
            bfr[ni] = *reinterpret_cast<const bf16x8*>(
                Bb + rB * 64 + ((kgrp ^ ((rB >> 1) & 3)) << 4));
        }
        __builtin_amdgcn_s_setprio(1);
#pragma unroll
        for (int mi = 0; mi < 8; ++mi) {
            const int rA = wr * 128 + mi * 16 + (lane & 15);
            bf16x8 af = *reinterpret_cast<const bf16x8*>(
                Ab + rA * 64 + ((kgrp ^ ((rA >> 1) & 3)) << 4));
            acc[mi][0] = __builtin_amdgcn_mfma_f32_16x16x32_bf16(af, bfr[0], acc[mi][0], 0, 0, 0);
            acc[mi][1] = __builtin_amdgcn_mfma_f32_16x16x32_bf16(af, bfr[1], acc[mi][1], 0, 0, 0);
        }
        __builtin_amdgcn_s_setprio(0);
    };

    stage(0); stage(1);
    for (int t = 0; t < NT - 2; ++t) {
        VMCNT(3);                        // own stage(t) done; stage(t+1) in flight
        __builtin_amdgcn_s_barrier();    // all waves' stage(t) done -> tile t resident
        CFENCE();
        stage(t + 2);                    // slot (t+2)%3 freed by step t-1 readers
        compute(t);
    }
    VMCNT(3);  __builtin_amdgcn_s_barrier(); CFENCE(); compute(NT - 2);
    VMCNT(0);  __builtin_amdgcn_s_barrier(); CFENCE(); compute(NT - 1);

    // Epilogue. C-frag: col = lane&15, row = (lane>>4)*4 + reg.
    float colpart[2] = {0.0f, 0.0f};
#pragma unroll
    for (int mi = 0; mi < 8; ++mi) {
#pragma unroll
        for (int reg = 0; reg < 4; ++reg) {
            const int grow = rowbase + wr * 128 + mi * 16 + ((lane >> 4) << 2) + reg;
            float rowpart = 0.0f;
#pragma unroll
            for (int ni = 0; ni < 2; ++ni) {
                const int gcol = colbase + wc * 32 + ni * 16 + (lane & 15);
                float e = __expf(acc[mi][ni][reg] * TAU_INV);
                if (diag && grow == gcol) e = 0.0f;
                rowpart += e;
                colpart[ni] += e;
            }
#pragma unroll
            for (int off = 1; off < 16; off <<= 1)
                rowpart += __shfl_xor(rowpart, off, 64);
            if ((lane & 15) == 0) atomicAdd(&rowsum[grow], rowpart);
        }
    }
    if (!diag) {
#pragma unroll
        for (int ni = 0; ni < 2; ++ni) {
            float cp = colpart[ni];
            cp += __shfl_xor(cp, 16, 64);
            cp += __shfl_xor(cp, 32, 64);
            if (lane < 16)
                atomicAdd(&rowsum[colbase + wc * 32 + ni * 16 + lane], cp);
        }
    }
}

// ---- Kernel C: loss = mean(log(denom) - pos/tau) ---------------------------
__global__ __launch_bounds__(256)
void loss_kernel(const float* __restrict__ rowsum, const float* __restrict__ pos,
                 float* __restrict__ out, int n_total, int n_half) {
    const int t = threadIdx.x;
    float acc = 0.0f;
    for (int r = t; r < n_total; r += 256) {
        const int pi = (r < n_half) ? r : (r - n_half);
        acc += logf(rowsum[r]) - TAU_INV * pos[pi];
    }
    acc = wave_reduce_add(acc);
    __shared__ float ws4[4];
    if ((t & 63) == 0) ws4[t >> 6] = acc;
    __syncthreads();
    if (t == 0) out[0] = (ws4[0] + ws4[1] + ws4[2] + ws4[3]) / (float)n_total;
}

extern "C" void kernel_launch(void* const* d_in, const int* in_sizes, int n_in,
                              void* d_out, int out_size, void* d_ws, size_t ws_size,
                              hipStream_t stream) {
    const float* zi = (const float*)d_in[0];
    const float* zj = (const float*)d_in[1];
    float* out = (float*)d_out;

    const int n_half  = in_sizes[0] / D_DIM;   // 4096
    const int n_total = 2 * n_half;            // 8192

    char* ws = (char*)d_ws;
    __hip_bfloat16* K = (__hip_bfloat16*)ws;
    size_t off = (size_t)n_total * D_DIM * sizeof(__hip_bfloat16);
    float* rowsum = (float*)(ws + off); off += (size_t)n_total * 4;
    float* pos    = (float*)(ws + off); off += (size_t)n_half * 4;

    norm_pos_kernel<<<n_half, 256, 0, stream>>>(zi, zj, K, rowsum, pos, n_half);

    // triangular 256x128 tiles: sum_{by=0}^{31} (64 - 2*by) = 1056 blocks
    const int nblk = 1056;
    simclr_gemm_kernel<<<nblk, 512, 0, stream>>>(K, rowsum, n_total);

    loss_kernel<<<1, 256, 0, stream>>>(rowsum, pos, out, n_total, n_half);
}